// Round 11
// baseline (1144.769 us; speedup 1.0000x reference)
//
#include <hip/hip_runtime.h>

typedef _Float16 half8 __attribute__((ext_vector_type(8)));
typedef unsigned short ushort8 __attribute__((ext_vector_type(8)));
typedef float floatx4 __attribute__((ext_vector_type(4)));
typedef unsigned short u16;

#define NROWS 115200
#define MT 16

__device__ __forceinline__ void splitf(float f, u16& hi, u16& lo) {
    _Float16 h = (_Float16)f;
    _Float16 l = (_Float16)(f - (float)h);
    hi = __builtin_bit_cast(u16, h);
    lo = __builtin_bit_cast(u16, l);
}

// swizzled index into a [16][256] fp16 LDS plane (16B-block XOR swizzle)
__device__ __forceinline__ int swz(int row, int col) {
    return row * 256 + ((((col >> 3)) ^ (row & 15)) << 3) + (col & 7);
}

__device__ __forceinline__ float theta0_at(int k, const float* ip, const float* is, const float* ic) {
    if (k < 144) return ip[k];
    if (k < 154) return is[k - 144];
    if (k < 157) return ic[k - 154];
    return 0.f;
}

// prep1: blocks 0..63 pack W1 -> split planes; blocks 64..83 compute W23=W2@W3
// (sequential-j fmaf), store fp32 copy, pack split planes, and b23.
__global__ void prep1(const float* __restrict__ W1, const float* __restrict__ W2,
                      const float* __restrict__ W3, const float* __restrict__ b2,
                      const float* __restrict__ b3,
                      u16* __restrict__ w1h, u16* __restrict__ w1l,
                      u16* __restrict__ w23h, u16* __restrict__ w23l,
                      float* __restrict__ w23f, float* __restrict__ b23f) {
    __shared__ float w3c[256][17];
    int b = blockIdx.x;
    int t = threadIdx.x;

    if (b < 64) {
        int nt = b >> 2;
        int frag = (b & 3) * 256 + t;
        if (frag >= 52 * 16) return;
        int kf = frag >> 4, m = frag & 15;
        int n = nt * 16 + m;
        ushort8 vh, vl;
        #pragma unroll
        for (int j = 0; j < 8; ++j) {
            int k = kf * 8 + j;
            float v = (k < 413 && n < 256) ? W1[(size_t)k * 256 + n] : 0.f;
            u16 hi, lo; splitf(v, hi, lo);
            vh[j] = hi; vl[j] = lo;
        }
        size_t o = ((size_t)nt * 52 + kf) * 128 + (size_t)m * 8;
        *(ushort8*)&w1h[o] = vh;
        *(ushort8*)&w1l[o] = vl;
        return;
    }

    int bb = b - 64;
    int bx = bb & 1, nt = bb >> 1;
    #pragma unroll
    for (int c = 0; c < 16; ++c) {
        int n = nt * 16 + c;
        w3c[t][c] = (n < 157) ? W3[(size_t)t * 157 + n] : 0.f;
    }
    __syncthreads();

    int frag = bx * 256 + t;
    int kf = frag >> 4, m = frag & 15;
    int n = nt * 16 + m;

    if (bx == 0 && kf == 0 && n < 157) {
        float acc = b3[n];
        for (int j = 0; j < 256; ++j) acc = fmaf(b2[j], w3c[j][m], acc);
        b23f[n] = acc;
    }

    ushort8 vh, vl;
    #pragma unroll
    for (int j = 0; j < 8; ++j) {
        int k = kf * 8 + j;
        const float* w2r = W2 + (size_t)k * 256;
        float acc = 0.f;
        for (int jj = 0; jj < 256; ++jj)
            acc = fmaf(w2r[jj], w3c[jj][m], acc);
        if (n < 157) w23f[(size_t)k * 157 + n] = acc;   // fp32 copy for prep2
        u16 hi, lo; splitf(acc, hi, lo);
        vh[j] = hi; vl[j] = lo;
    }
    size_t o = ((size_t)nt * 32 + kf) * 128 + (size_t)m * 8;
    *(ushort8*)&w23h[o] = vh;
    *(ushort8*)&w23l[o] = vl;
}

// prep2: grid (2,17).
//  y<16: pack W231 = W23 @ W1theta (256x256), computed on the fly from w23f.
//  y==16,x==0: vectors b1p = b1 + theta0@W1theta, b231 = b23@W1theta,
//              bfin = theta0 + 3*b23 (padded to 160).
__global__ void prep2(const float* __restrict__ W1, const float* __restrict__ w23f,
                      const float* __restrict__ b23f, const float* __restrict__ b1,
                      const float* __restrict__ ip, const float* __restrict__ is,
                      const float* __restrict__ ic,
                      u16* __restrict__ w231h, u16* __restrict__ w231l,
                      float* __restrict__ b1p, float* __restrict__ b231,
                      float* __restrict__ bfin) {
    int t = threadIdx.x;
    if (blockIdx.y == 16) {
        if (blockIdx.x != 0) return;
        int n = t;   // 0..255
        float u0 = 0.f, bb = 0.f;
        for (int k = 0; k < 157; ++k) {
            float w = W1[(size_t)(256 + k) * 256 + n];
            u0 = fmaf(theta0_at(k, ip, is, ic), w, u0);
            bb = fmaf(b23f[k], w, bb);
        }
        b1p[n] = b1[n] + u0;
        b231[n] = bb;
        if (t < 160)
            bfin[t] = (t < 157) ? theta0_at(t, ip, is, ic) + 3.f * b23f[t] : 0.f;
        return;
    }
    int nt = blockIdx.y;
    int frag = blockIdx.x * 256 + t;      // kf 0..31
    int kf = frag >> 4, m = frag & 15;
    int n = nt * 16 + m;
    ushort8 vh, vl;
    #pragma unroll
    for (int j = 0; j < 8; ++j) {
        int a = kf * 8 + j;
        float acc = 0.f;
        for (int k = 0; k < 157; ++k)
            acc = fmaf(w23f[(size_t)a * 157 + k], W1[(size_t)(256 + k) * 256 + n], acc);
        u16 hi, lo; splitf(acc, hi, lo);
        vh[j] = hi; vl[j] = lo;
    }
    size_t o = ((size_t)nt * 32 + kf) * 128 + (size_t)m * 8;
    *(ushort8*)&w231h[o] = vh;
    *(ushort8*)&w231l[o] = vl;
}

// ZERO-BARRIER kernel: 64 threads = ONE wave owns 16 rows x ALL 256 cols.
// The g exchange (C-frag -> A-frag transpose) goes through wave-PRIVATE LDS:
// per-wave ds ops are program-ordered (compiler lgkmcnt), no __syncthreads.
// One 16KB plane pair serves x -> g0 -> g1 -> G -> thf successively.
// u-space math (r9): P = hx+u+b1p in regs; per-element accumulation order
// bit-identical to r9. 16 independent MFMA chains per phase per wave.
// __launch_bounds__ 2nd arg = min BLOCKS/CU on this toolchain (r5/r6):
// (64,8) -> 8 waves/CU -> 2 waves/SIMD -> VGPR cap 256 (natural ~220).
__global__ __launch_bounds__(64, 8) void fused_head(
    const float* __restrict__ xg,
    const u16* __restrict__ w1h, const u16* __restrict__ w1l,
    const u16* __restrict__ w231h, const u16* __restrict__ w231l,
    const u16* __restrict__ w23h, const u16* __restrict__ w23l,
    const float* __restrict__ b1p, const float* __restrict__ b231,
    const float* __restrict__ bfin,
    float* __restrict__ out)
{
    // 16384 B static LDS: one split-fp16 plane pair [16][256]
    __shared__ __align__(16) u16 smem[8192];
    u16* Ph = smem;             // hi plane (x, then g0, g1, G)
    u16* Pl = smem + 4096;      // lo plane
    float* thf = (float*)smem;  // [16][144] fp32 pose (final; overlays planes)

    const int t = threadIdx.x;              // one wave
    const int q = t >> 4, m = t & 15;       // quad, lane-in-16
    const int fb = q * 128 + m * 8;         // fragment-local B offset
    const long rowbase = (long)blockIdx.x * MT;

    // ---- stage x tile (16 rows x 256 fp32 -> split fp16 planes) ----
    #pragma unroll
    for (int i = 0; i < 8; ++i) {
        int idx = t + i * 64;
        int r = idx >> 5, s = idx & 31;
        const float4* sp = (const float4*)(xg + (rowbase + r) * 256 + s * 8);
        float4 f0 = sp[0], f1 = sp[1];
        float fv[8] = {f0.x, f0.y, f0.z, f0.w, f1.x, f1.y, f1.z, f1.w};
        ushort8 vh, vl;
        #pragma unroll
        for (int j = 0; j < 8; ++j) {
            u16 hi, lo; splitf(fv[j], hi, lo);
            vh[j] = hi; vl[j] = lo;
        }
        int o = r * 256 + ((s ^ (r & 15)) << 3);
        *(ushort8*)&Ph[o] = vh;
        *(ushort8*)&Pl[o] = vl;
    }
    // no barrier: wave-local LDS, ds ops ordered by lgkmcnt

    const floatx4 zero4 = {0.f, 0.f, 0.f, 0.f};
    floatx4 P[16], G[16];
    #pragma unroll
    for (int ct = 0; ct < 16; ++ct) { P[ct] = zero4; G[ct] = zero4; }

    // ============ P = x @ W1x (K=256) + b1p ============
    #pragma unroll 2
    for (int ks = 0; ks < 8; ++ks) {
        int o = swz(m, ks * 32 + q * 8);
        half8 ah = *(const half8*)&Ph[o];
        half8 al = *(const half8*)&Pl[o];
        int bbase = ks * 512 + fb;
        #pragma unroll
        for (int ct = 0; ct < 16; ++ct) {
            half8 bh = *(const half8*)(w1h + bbase + ct * 6656);
            half8 bl = *(const half8*)(w1l + bbase + ct * 6656);
            P[ct] = __builtin_amdgcn_mfma_f32_16x16x32_f16(ah, bh, P[ct], 0, 0, 0);
            P[ct] = __builtin_amdgcn_mfma_f32_16x16x32_f16(al, bh, P[ct], 0, 0, 0);
            P[ct] = __builtin_amdgcn_mfma_f32_16x16x32_f16(ah, bl, P[ct], 0, 0, 0);
        }
    }
    #pragma unroll
    for (int ct = 0; ct < 16; ++ct) {
        float bv = b1p[ct * 16 + m];
        #pragma unroll
        for (int r = 0; r < 4; ++r) P[ct][r] += bv;
    }

    // ============ 3 iterations, no barriers ============
    #pragma unroll
    for (int it = 0; it < 3; ++it) {
        // g = relu(P); G += g; stage g (it<2) or G (it==2) into the plane pair.
        // Overwrites the plane just consumed -- safe: wave-local ordering.
        #pragma unroll
        for (int ct = 0; ct < 16; ++ct) {
            int n = ct * 16 + m;
            #pragma unroll
            for (int r = 0; r < 4; ++r) {
                int row = q * 4 + r;
                float g = fmaxf(P[ct][r], 0.f);
                G[ct][r] += g;
                float st = (it == 2) ? G[ct][r] : g;
                u16 hi, lo; splitf(st, hi, lo);
                int o = swz(row, n);
                Ph[o] = hi; Pl[o] = lo;
            }
        }

        if (it < 2) {
            // P += g @ W231 + b231   (K=256, N=256)
            #pragma unroll 2
            for (int ks = 0; ks < 8; ++ks) {
                int o = swz(m, ks * 32 + q * 8);
                half8 ah = *(const half8*)&Ph[o];
                half8 al = *(const half8*)&Pl[o];
                int bbase = ks * 512 + fb;
                #pragma unroll
                for (int ct = 0; ct < 16; ++ct) {
                    half8 bh = *(const half8*)(w231h + bbase + ct * 4096);
                    half8 bl = *(const half8*)(w231l + bbase + ct * 4096);
                    P[ct] = __builtin_amdgcn_mfma_f32_16x16x32_f16(ah, bh, P[ct], 0, 0, 0);
                    P[ct] = __builtin_amdgcn_mfma_f32_16x16x32_f16(al, bh, P[ct], 0, 0, 0);
                    P[ct] = __builtin_amdgcn_mfma_f32_16x16x32_f16(ah, bl, P[ct], 0, 0, 0);
                }
            }
            #pragma unroll
            for (int ct = 0; ct < 16; ++ct) {
                float bv = b231[ct * 16 + m];
                #pragma unroll
                for (int r = 0; r < 4; ++r) P[ct][r] += bv;
            }
        }
    }

    // ============ final: theta = G @ W23 + bfin (G staged in planes) ============
    floatx4 a3[10];
    #pragma unroll
    for (int nt = 0; nt < 10; ++nt) a3[nt] = zero4;

    #pragma unroll 2
    for (int ks = 0; ks < 8; ++ks) {
        int o = swz(m, ks * 32 + q * 8);
        half8 ah = *(const half8*)&Ph[o];
        half8 al = *(const half8*)&Pl[o];
        int bbase = ks * 512 + fb;
        #pragma unroll
        for (int nt = 0; nt < 10; ++nt) {
            half8 bh = *(const half8*)(w23h + bbase + nt * 4096);
            half8 bl = *(const half8*)(w23l + bbase + nt * 4096);
            a3[nt] = __builtin_amdgcn_mfma_f32_16x16x32_f16(ah, bh, a3[nt], 0, 0, 0);
            a3[nt] = __builtin_amdgcn_mfma_f32_16x16x32_f16(al, bh, a3[nt], 0, 0, 0);
            a3[nt] = __builtin_amdgcn_mfma_f32_16x16x32_f16(ah, bl, a3[nt], 0, 0, 0);
        }
    }
    // theta = a3 + bfin; pose -> thf (overlays planes; all plane reads above
    // precede these aliasing writes in program order -> wave-local safe);
    // betas/camera -> global
    #pragma unroll
    for (int nt = 0; nt < 10; ++nt) {
        int n3 = nt * 16 + m;
        float bv = bfin[n3];
        if (nt < 9) {
            #pragma unroll
            for (int r = 0; r < 4; ++r) {
                int row = q * 4 + r;
                thf[row * 144 + n3] = a3[nt][r] + bv;
            }
        } else {  // tile 9: cols 144..159 = betas + camera
            #pragma unroll
            for (int r = 0; r < 4; ++r) {
                int row = q * 4 + r;
                long grow = rowbase + row;
                float v = a3[nt][r] + bv;
                if (m < 10)
                    out[(size_t)NROWS * 216 + grow * 10 + m] = v;
                else if (m < 13)
                    out[(size_t)NROWS * 216 + (size_t)NROWS * 10 + grow * 3 + (m - 10)] = v;
            }
        }
    }

    // ============ epilogue: rot6d -> rotmat (fp32), 4 lanes/row ============
    {
        int r = t >> 2, g4 = t & 3;    // 16 rows x 4 lanes, 6 joints each
        long grow = rowbase + r;
        #pragma unroll
        for (int jj = 0; jj < 6; ++jj) {
            int j = g4 * 6 + jj;
            const float* p = &thf[r * 144 + j * 6];
            float a1x = p[0], a2x = p[1], a1y = p[2], a2y = p[3], a1z = p[4], a2z = p[5];
            float n1 = fmaxf(sqrtf(a1x * a1x + a1y * a1y + a1z * a1z), 1e-12f);
            float b1x = a1x / n1, b1y = a1y / n1, b1z = a1z / n1;
            float d = b1x * a2x + b1y * a2y + b1z * a2z;
            float ux = a2x - d * b1x, uy = a2y - d * b1y, uz = a2z - d * b1z;
            float n2 = fmaxf(sqrtf(ux * ux + uy * uy + uz * uz), 1e-12f);
            float b2x = ux / n2, b2y = uy / n2, b2z = uz / n2;
            float b3x = b1y * b2z - b1z * b2y;
            float b3y = b1z * b2x - b1x * b2z;
            float b3z = b1x * b2y - b1y * b2x;
            float* o = out + (size_t)grow * 216 + j * 9;
            o[0] = b1x; o[1] = b2x; o[2] = b3x;
            o[3] = b1y; o[4] = b2y; o[5] = b3y;
            o[6] = b1z; o[7] = b2z; o[8] = b3z;
        }
    }
}

extern "C" void kernel_launch(void* const* d_in, const int* in_sizes, int n_in,
                              void* d_out, int out_size, void* d_ws, size_t ws_size,
                              hipStream_t stream) {
    const float* x  = (const float*)d_in[0];
    const float* W1 = (const float*)d_in[2];
    const float* b1 = (const float*)d_in[3];
    const float* W2 = (const float*)d_in[4];
    const float* b2 = (const float*)d_in[5];
    const float* W3 = (const float*)d_in[6];
    const float* b3 = (const float*)d_in[7];
    const float* ip = (const float*)d_in[8];
    const float* is = (const float*)d_in[9];
    const float* ic = (const float*)d_in[10];

    u16* w1h   = (u16*)d_ws;                 // 16nt * 52kf * 128 = 106496
    u16* w1l   = w1h + 106496;
    u16* w23h  = w1l + 106496;               // 10nt * 32kf * 128 = 40960
    u16* w23l  = w23h + 40960;
    u16* w231h = w23l + 40960;               // 16nt * 32kf * 128 = 65536
    u16* w231l = w231h + 65536;
    float* w23f = (float*)(w231l + 65536);   // 256*157 fp32
    float* b23f = w23f + 256 * 157;          // 157
    float* b1p  = b23f + 157;                // 256
    float* b231 = b1p + 256;                 // 256
    float* bfin = b231 + 256;                // 160

    prep1<<<84, 256, 0, stream>>>(W1, W2, W3, b2, b3, w1h, w1l, w23h, w23l, w23f, b23f);
    prep2<<<dim3(2, 17), 256, 0, stream>>>(W1, w23f, b23f, b1, ip, is, ic,
                                           w231h, w231l, b1p, b231, bfin);

    fused_head<<<NROWS / MT, 64, 0, stream>>>(x, w1h, w1l, w231h, w231l, w23h, w23l,
                                              b1p, b231, bfin, (float*)d_out);
}

// Round 12
// 585.743 us; speedup vs baseline: 1.9544x; 1.9544x over previous
//
#include <hip/hip_runtime.h>

typedef _Float16 half8 __attribute__((ext_vector_type(8)));
typedef unsigned short ushort8 __attribute__((ext_vector_type(8)));
typedef float floatx4 __attribute__((ext_vector_type(4)));
typedef unsigned short u16;

#define NROWS 115200
#define MT 32

__device__ __forceinline__ void splitf(float f, u16& hi, u16& lo) {
    _Float16 h = (_Float16)f;
    _Float16 l = (_Float16)(f - (float)h);
    hi = __builtin_bit_cast(u16, h);
    lo = __builtin_bit_cast(u16, l);
}

// swizzled index into a [32][256] fp16 LDS plane (16B-block XOR swizzle)
__device__ __forceinline__ int swz(int row, int col) {
    return row * 256 + ((((col >> 3)) ^ (row & 31)) << 3) + (col & 7);
}

__device__ __forceinline__ float theta0_at(int k, const float* ip, const float* is, const float* ic) {
    if (k < 144) return ip[k];
    if (k < 154) return is[k - 144];
    if (k < 157) return ic[k - 154];
    return 0.f;
}

// prep1: blocks 0..63 pack W1 -> split planes; blocks 64..83 compute W23=W2@W3
// (sequential-j fmaf), store fp32 copy, pack split planes, and b23.
__global__ void prep1(const float* __restrict__ W1, const float* __restrict__ W2,
                      const float* __restrict__ W3, const float* __restrict__ b2,
                      const float* __restrict__ b3,
                      u16* __restrict__ w1h, u16* __restrict__ w1l,
                      u16* __restrict__ w23h, u16* __restrict__ w23l,
                      float* __restrict__ w23f, float* __restrict__ b23f) {
    __shared__ float w3c[256][17];
    int b = blockIdx.x;
    int t = threadIdx.x;

    if (b < 64) {
        int nt = b >> 2;
        int frag = (b & 3) * 256 + t;
        if (frag >= 52 * 16) return;
        int kf = frag >> 4, m = frag & 15;
        int n = nt * 16 + m;
        ushort8 vh, vl;
        #pragma unroll
        for (int j = 0; j < 8; ++j) {
            int k = kf * 8 + j;
            float v = (k < 413 && n < 256) ? W1[(size_t)k * 256 + n] : 0.f;
            u16 hi, lo; splitf(v, hi, lo);
            vh[j] = hi; vl[j] = lo;
        }
        size_t o = ((size_t)nt * 52 + kf) * 128 + (size_t)m * 8;
        *(ushort8*)&w1h[o] = vh;
        *(ushort8*)&w1l[o] = vl;
        return;
    }

    int bb = b - 64;
    int bx = bb & 1, nt = bb >> 1;
    #pragma unroll
    for (int c = 0; c < 16; ++c) {
        int n = nt * 16 + c;
        w3c[t][c] = (n < 157) ? W3[(size_t)t * 157 + n] : 0.f;
    }
    __syncthreads();

    int frag = bx * 256 + t;
    int kf = frag >> 4, m = frag & 15;
    int n = nt * 16 + m;

    if (bx == 0 && kf == 0 && n < 157) {
        float acc = b3[n];
        for (int j = 0; j < 256; ++j) acc = fmaf(b2[j], w3c[j][m], acc);
        b23f[n] = acc;
    }

    ushort8 vh, vl;
    #pragma unroll
    for (int j = 0; j < 8; ++j) {
        int k = kf * 8 + j;
        const float* w2r = W2 + (size_t)k * 256;
        float acc = 0.f;
        for (int jj = 0; jj < 256; ++jj)
            acc = fmaf(w2r[jj], w3c[jj][m], acc);
        if (n < 157) w23f[(size_t)k * 157 + n] = acc;   // fp32 copy for prep2
        u16 hi, lo; splitf(acc, hi, lo);
        vh[j] = hi; vl[j] = lo;
    }
    size_t o = ((size_t)nt * 32 + kf) * 128 + (size_t)m * 8;
    *(ushort8*)&w23h[o] = vh;
    *(ushort8*)&w23l[o] = vl;
}

// prep2: grid (2,17).
//  y<16: pack W231 = W23 @ W1theta (256x256), computed on the fly from w23f.
//  y==16,x==0: vectors b1p = b1 + theta0@W1theta, b231 = b23@W1theta,
//              bfin = theta0 + 3*b23 (padded to 160).
__global__ void prep2(const float* __restrict__ W1, const float* __restrict__ w23f,
                      const float* __restrict__ b23f, const float* __restrict__ b1,
                      const float* __restrict__ ip, const float* __restrict__ is,
                      const float* __restrict__ ic,
                      u16* __restrict__ w231h, u16* __restrict__ w231l,
                      float* __restrict__ b1p, float* __restrict__ b231,
                      float* __restrict__ bfin) {
    int t = threadIdx.x;
    if (blockIdx.y == 16) {
        if (blockIdx.x != 0) return;
        int n = t;   // 0..255
        float u0 = 0.f, bb = 0.f;
        for (int k = 0; k < 157; ++k) {
            float w = W1[(size_t)(256 + k) * 256 + n];
            u0 = fmaf(theta0_at(k, ip, is, ic), w, u0);
            bb = fmaf(b23f[k], w, bb);
        }
        b1p[n] = b1[n] + u0;
        b231[n] = bb;
        if (t < 160)
            bfin[t] = (t < 157) ? theta0_at(t, ip, is, ic) + 3.f * b23f[t] : 0.f;
        return;
    }
    int nt = blockIdx.y;
    int frag = blockIdx.x * 256 + t;      // kf 0..31
    int kf = frag >> 4, m = frag & 15;
    int n = nt * 16 + m;
    ushort8 vh, vl;
    #pragma unroll
    for (int j = 0; j < 8; ++j) {
        int a = kf * 8 + j;
        float acc = 0.f;
        for (int k = 0; k < 157; ++k)
            acc = fmaf(w23f[(size_t)a * 157 + k], W1[(size_t)(256 + k) * 256 + n], acc);
        u16 hi, lo; splitf(acc, hi, lo);
        vh[j] = hi; vl[j] = lo;
    }
    size_t o = ((size_t)nt * 32 + kf) * 128 + (size_t)m * 8;
    *(ushort8*)&w231h[o] = vh;
    *(ushort8*)&w231l[o] = vl;
}

// 256 threads = 4 waves, MT=32 (rt=2), SINGLE-buffered plane pair = 32 KB LDS.
// Combines r10's halved per-row weight traffic with r9-level residency:
// LDS admits 5 blocks/CU; natural VGPR ~100 (r10) -> 5 waves/SIMD -> 20
// waves/CU. 2 barriers/iter (WAR+RAW) = 9 per 32 rows ~= r9's 10 per 32.
// u-space math bit-identical to r9/r10. __launch_bounds__ 2nd arg = min
// BLOCKS/CU on this toolchain: (256,4) -> VGPR cap 128 (natural ~100, clean).
__global__ __launch_bounds__(256, 4) void fused_head(
    const float* __restrict__ xg,
    const u16* __restrict__ w1h, const u16* __restrict__ w1l,
    const u16* __restrict__ w231h, const u16* __restrict__ w231l,
    const u16* __restrict__ w23h, const u16* __restrict__ w23l,
    const float* __restrict__ b1p, const float* __restrict__ b231,
    const float* __restrict__ bfin,
    float* __restrict__ out)
{
    // 32768 B static LDS: ONE split-fp16 plane pair [32][256]
    __shared__ __align__(16) u16 smem[16384];
    u16* Ph = smem;             // hi plane (x, then g0, g1, G)
    u16* Pl = smem + 8192;      // lo plane
    float* thf = (float*)smem;  // [32][144] fp32 pose (final; overlays planes)

    const int t = threadIdx.x;
    const int lid = t & 63, wv = t >> 6;       // 4 waves
    const int q = lid >> 4, m = lid & 15;      // quad, lane-in-16
    const int fb = q * 128 + m * 8;            // fragment-local B offset
    const long rowbase = (long)blockIdx.x * MT;

    // ---- stage x tile (32 rows x 256 fp32 -> split fp16 planes) ----
    #pragma unroll
    for (int i = 0; i < 4; ++i) {
        int idx = t + i * 256;
        int r = idx >> 5, s = idx & 31;
        const float4* sp = (const float4*)(xg + (rowbase + r) * 256 + s * 8);
        float4 f0 = sp[0], f1 = sp[1];
        float fv[8] = {f0.x, f0.y, f0.z, f0.w, f1.x, f1.y, f1.z, f1.w};
        ushort8 vh, vl;
        #pragma unroll
        for (int j = 0; j < 8; ++j) {
            u16 hi, lo; splitf(fv[j], hi, lo);
            vh[j] = hi; vl[j] = lo;
        }
        int o = r * 256 + ((s ^ (r & 31)) << 3);
        *(ushort8*)&Ph[o] = vh;
        *(ushort8*)&Pl[o] = vl;
    }
    __syncthreads();   // bar 1: x staged

    const floatx4 zero4 = {0.f, 0.f, 0.f, 0.f};
    floatx4 P[4][2], G[4][2];
    #pragma unroll
    for (int ct = 0; ct < 4; ++ct)
        #pragma unroll
        for (int rt = 0; rt < 2; ++rt) { P[ct][rt] = zero4; G[ct][rt] = zero4; }

    // ============ P = x @ W1x (K=256) + b1p ============
    #pragma unroll 2
    for (int ks = 0; ks < 8; ++ks) {
        half8 ah[2], al[2];
        #pragma unroll
        for (int rt = 0; rt < 2; ++rt) {
            int o = swz(rt * 16 + m, ks * 32 + q * 8);
            ah[rt] = *(const half8*)&Ph[o];
            al[rt] = *(const half8*)&Pl[o];
        }
        int bbase = wv * 26624 + ks * 512 + fb;
        #pragma unroll
        for (int ct = 0; ct < 4; ++ct) {
            half8 bh = *(const half8*)(w1h + bbase + ct * 6656);
            half8 bl = *(const half8*)(w1l + bbase + ct * 6656);
            #pragma unroll
            for (int rt = 0; rt < 2; ++rt) {
                P[ct][rt] = __builtin_amdgcn_mfma_f32_16x16x32_f16(ah[rt], bh, P[ct][rt], 0, 0, 0);
                P[ct][rt] = __builtin_amdgcn_mfma_f32_16x16x32_f16(al[rt], bh, P[ct][rt], 0, 0, 0);
                P[ct][rt] = __builtin_amdgcn_mfma_f32_16x16x32_f16(ah[rt], bl, P[ct][rt], 0, 0, 0);
            }
        }
    }
    #pragma unroll
    for (int ct = 0; ct < 4; ++ct) {
        float bv = b1p[wv * 64 + ct * 16 + m];
        #pragma unroll
        for (int rt = 0; rt < 2; ++rt)
            #pragma unroll
            for (int r = 0; r < 4; ++r) P[ct][rt][r] += bv;
    }

    // ============ 3 iterations: WAR bar, write, RAW bar, gemm ============
    #pragma unroll
    for (int it = 0; it < 3; ++it) {
        __syncthreads();   // WAR: all reads of planes done (x / g0 / g1)
        // g = relu(P); G += g; stage g (it<2) or G (it==2)
        #pragma unroll
        for (int ct = 0; ct < 4; ++ct) {
            int n = wv * 64 + ct * 16 + m;
            #pragma unroll
            for (int rt = 0; rt < 2; ++rt)
                #pragma unroll
                for (int r = 0; r < 4; ++r) {
                    int row = rt * 16 + q * 4 + r;
                    float g = fmaxf(P[ct][rt][r], 0.f);
                    G[ct][rt][r] += g;
                    float st = (it == 2) ? G[ct][rt][r] : g;
                    u16 hi, lo; splitf(st, hi, lo);
                    int o = swz(row, n);
                    Ph[o] = hi; Pl[o] = lo;
                }
        }
        __syncthreads();   // RAW: staged plane visible

        if (it < 2) {
            // P += g @ W231 + b231   (K=256, N=256)
            #pragma unroll 2
            for (int ks = 0; ks < 8; ++ks) {
                half8 ah[2], al[2];
                #pragma unroll
                for (int rt = 0; rt < 2; ++rt) {
                    int o = swz(rt * 16 + m, ks * 32 + q * 8);
                    ah[rt] = *(const half8*)&Ph[o];
                    al[rt] = *(const half8*)&Pl[o];
                }
                int bbase = wv * 16384 + ks * 512 + fb;
                #pragma unroll
                for (int ct = 0; ct < 4; ++ct) {
                    half8 bh = *(const half8*)(w231h + bbase + ct * 4096);
                    half8 bl = *(const half8*)(w231l + bbase + ct * 4096);
                    #pragma unroll
                    for (int rt = 0; rt < 2; ++rt) {
                        P[ct][rt] = __builtin_amdgcn_mfma_f32_16x16x32_f16(ah[rt], bh, P[ct][rt], 0, 0, 0);
                        P[ct][rt] = __builtin_amdgcn_mfma_f32_16x16x32_f16(al[rt], bh, P[ct][rt], 0, 0, 0);
                        P[ct][rt] = __builtin_amdgcn_mfma_f32_16x16x32_f16(ah[rt], bl, P[ct][rt], 0, 0, 0);
                    }
                }
            }
            #pragma unroll
            for (int ct = 0; ct < 4; ++ct) {
                float bv = b231[wv * 64 + ct * 16 + m];
                #pragma unroll
                for (int rt = 0; rt < 2; ++rt)
                    #pragma unroll
                    for (int r = 0; r < 4; ++r) P[ct][rt][r] += bv;
            }
        }
    }

    // ============ final: theta = G @ W23 + bfin (G staged in planes) ============
    const int ncts = (wv < 2) ? 3 : 2;   // tiles wv + c*4, 0..9
    floatx4 a3[3][2];
    #pragma unroll
    for (int c = 0; c < 3; ++c)
        #pragma unroll
        for (int rt = 0; rt < 2; ++rt) a3[c][rt] = zero4;

    #pragma unroll 2
    for (int ks = 0; ks < 8; ++ks) {
        half8 ah[2], al[2];
        #pragma unroll
        for (int rt = 0; rt < 2; ++rt) {
            int o = swz(rt * 16 + m, ks * 32 + q * 8);
            ah[rt] = *(const half8*)&Ph[o];
            al[rt] = *(const half8*)&Pl[o];
        }
        int bbase = ks * 512 + fb;
        #pragma unroll
        for (int c = 0; c < 3; ++c) {
            if (c < ncts) {
                half8 bh = *(const half8*)(w23h + bbase + (wv + c * 4) * 4096);
                half8 bl = *(const half8*)(w23l + bbase + (wv + c * 4) * 4096);
                #pragma unroll
                for (int rt = 0; rt < 2; ++rt) {
                    a3[c][rt] = __builtin_amdgcn_mfma_f32_16x16x32_f16(ah[rt], bh, a3[c][rt], 0, 0, 0);
                    a3[c][rt] = __builtin_amdgcn_mfma_f32_16x16x32_f16(al[rt], bh, a3[c][rt], 0, 0, 0);
                    a3[c][rt] = __builtin_amdgcn_mfma_f32_16x16x32_f16(ah[rt], bl, a3[c][rt], 0, 0, 0);
                }
            }
        }
    }
    __syncthreads();   // WAR: all G reads done -> thf may overlay planes

    // theta = a3 + bfin; pose -> thf; betas/camera -> global
    #pragma unroll
    for (int c = 0; c < 3; ++c) {
        if (c < ncts) {
            int tile = wv + c * 4;
            int n3 = tile * 16 + m;
            float bv = bfin[n3];
            if (tile < 9) {
                #pragma unroll
                for (int rt = 0; rt < 2; ++rt)
                    #pragma unroll
                    for (int r = 0; r < 4; ++r) {
                        int row = rt * 16 + q * 4 + r;
                        thf[row * 144 + n3] = a3[c][rt][r] + bv;
                    }
            } else {  // tile 9: cols 144..159 = betas + camera
                #pragma unroll
                for (int rt = 0; rt < 2; ++rt)
                    #pragma unroll
                    for (int r = 0; r < 4; ++r) {
                        int row = rt * 16 + q * 4 + r;
                        long grow = rowbase + row;
                        float v = a3[c][rt][r] + bv;
                        if (m < 10)
                            out[(size_t)NROWS * 216 + grow * 10 + m] = v;
                        else if (m < 13)
                            out[(size_t)NROWS * 216 + (size_t)NROWS * 10 + grow * 3 + (m - 10)] = v;
                    }
            }
        }
    }
    __syncthreads();   // RAW: thf visible

    // ============ epilogue: rot6d -> rotmat (fp32), 8 threads/row ============
    {
        int r = t >> 3, g = t & 7;     // 32 rows x 8 threads, 3 consecutive joints each
        long grow = rowbase + r;
        #pragma unroll
        for (int jj = 0; jj < 3; ++jj) {
            int j = g * 3 + jj;
            const float* p = &thf[r * 144 + j * 6];
            float a1x = p[0], a2x = p[1], a1y = p[2], a2y = p[3], a1z = p[4], a2z = p[5];
            float n1 = fmaxf(sqrtf(a1x * a1x + a1y * a1y + a1z * a1z), 1e-12f);
            float b1x = a1x / n1, b1y = a1y / n1, b1z = a1z / n1;
            float d = b1x * a2x + b1y * a2y + b1z * a2z;
            float ux = a2x - d * b1x, uy = a2y - d * b1y, uz = a2z - d * b1z;
            float n2 = fmaxf(sqrtf(ux * ux + uy * uy + uz * uz), 1e-12f);
            float b2x = ux / n2, b2y = uy / n2, b2z = uz / n2;
            float b3x = b1y * b2z - b1z * b2y;
            float b3y = b1z * b2x - b1x * b2z;
            float b3z = b1x * b2y - b1y * b2x;
            float* o = out + (size_t)grow * 216 + j * 9;
            o[0] = b1x; o[1] = b2x; o[2] = b3x;
            o[3] = b1y; o[4] = b2y; o[5] = b3y;
            o[6] = b1z; o[7] = b2z; o[8] = b3z;
        }
    }
}

extern "C" void kernel_launch(void* const* d_in, const int* in_sizes, int n_in,
                              void* d_out, int out_size, void* d_ws, size_t ws_size,
                              hipStream_t stream) {
    const float* x  = (const float*)d_in[0];
    const float* W1 = (const float*)d_in[2];
    const float* b1 = (const float*)d_in[3];
    const float* W2 = (const float*)d_in[4];
    const float* b2 = (const float*)d_in[5];
    const float* W3 = (const float*)d_in[6];
    const float* b3 = (const float*)d_in[7];
    const float* ip = (const float*)d_in[8];
    const float* is = (const float*)d_in[9];
    const float* ic = (const float*)d_in[10];

    u16* w1h   = (u16*)d_ws;                 // 16nt * 52kf * 128 = 106496
    u16* w1l   = w1h + 106496;
    u16* w23h  = w1l + 106496;               // 10nt * 32kf * 128 = 40960
    u16* w23l  = w23h + 40960;
    u16* w231h = w23l + 40960;               // 16nt * 32kf * 128 = 65536
    u16* w231l = w231h + 65536;
    float* w23f = (float*)(w231l + 65536);   // 256*157 fp32
    float* b23f = w23f + 256 * 157;          // 157
    float* b1p  = b23f + 157;                // 256
    float* b231 = b1p + 256;                 // 256
    float* bfin = b231 + 256;                // 160

    prep1<<<84, 256, 0, stream>>>(W1, W2, W3, b2, b3, w1h, w1l, w23h, w23l, w23f, b23f);
    prep2<<<dim3(2, 17), 256, 0, stream>>>(W1, w23f, b23f, b1, ip, is, ic,
                                           w231h, w231l, b1p, b231, bfin);

    fused_head<<<NROWS / MT, 256, 0, stream>>>(x, w1h, w1l, w231h, w231l, w23h, w23l,
                                               b1p, b231, bfin, (float*)d_out);
}